// Round 1
// baseline (1397.430 us; speedup 1.0000x reference)
//
#include <hip/hip_runtime.h>
#include <hip/hip_fp16.h>

#define TT 512
#define BB 4096
#define HH 16

// ---------- math helpers ----------
__device__ __forceinline__ float rcp_(float x) { return __builtin_amdgcn_rcpf(x); }

__device__ __forceinline__ float tanh_(float x) {
    // tanh(x) = (e^{2x}-1)/(e^{2x}+1); clamp to avoid inf/inf (tanh saturates anyway)
    float xx = fminf(x, 15.0f);
    float e  = __expf(2.0f * xx);
    return (e - 1.0f) * rcp_(e + 1.0f);
}

__device__ __forceinline__ float elu_(float x) {
    return (x > 0.0f) ? x : (__expf(x) - 1.0f);
}

// broadcast value from lane l (compile-time constant after unroll) -> SGPR
__device__ __forceinline__ float bcast_(float v, int l) {
    return __uint_as_float(__builtin_amdgcn_readlane(__float_as_uint(v), l));
}

// load 16 halfs -> 16 floats (two 16B vector loads)
__device__ __forceinline__ void load16h_(const __half* p, float* o) {
    float4 r0 = ((const float4*)p)[0];
    float4 r1 = ((const float4*)p)[1];
    const __half2* a = (const __half2*)&r0;
    const __half2* b = (const __half2*)&r1;
#pragma unroll
    for (int k = 0; k < 4; ++k) { float2 f = __half22float2(a[k]); o[2*k] = f.x; o[2*k+1] = f.y; }
#pragma unroll
    for (int k = 0; k < 4; ++k) { float2 f = __half22float2(b[k]); o[8+2*k] = f.x; o[8+2*k+1] = f.y; }
}

// ---------- LSTM cell step ----------
// Lane l holds preactivation for gate row l (0-15:i, 16-31:f, 32-47:g, 48-63:o).
// c is the replicated cell state for hidden index (lane&15). h[16] replicated.
__device__ __forceinline__ float cellstep_(float g, int lane, float& c, float h[16]) {
    bool isT = ((lane >> 4) == 2);
    // sigmoid(x) = 0.5*tanh(0.5x)+0.5 -> single transcendental path, no divergence
    float y  = isT ? g : 0.5f * g;
    float th = tanh_(y);
    float a  = isT ? th : fmaf(0.5f, th, 0.5f);

    int j = lane & 15;
    float iv = __shfl(a, j);
    float fv = __shfl(a, j + 16);
    float gv = __shfl(a, j + 32);
    float ov = __shfl(a, j + 48);

    c = fmaf(fv, c, iv * gv);
    float hj = ov * tanh_(c);

#pragma unroll
    for (int k = 0; k < 16; ++k) h[k] = bcast_(hj, k);
    return hj;
}

// ---------- layer 0 (input dim 1), one direction ----------
__device__ void lstm0_(const float* __restrict__ xrow,
                       const float* __restrict__ Wih, const float* __restrict__ Whh,
                       const float* __restrict__ bih, const float* __restrict__ bhh,
                       int dir, __half* __restrict__ hout, size_t strideT,
                       int lane, float hfin[16]) {
    float whh[16];
#pragma unroll
    for (int k = 0; k < 4; ++k) {
        float4 v = ((const float4*)(Whh + lane * 16))[k];
        whh[4*k] = v.x; whh[4*k+1] = v.y; whh[4*k+2] = v.z; whh[4*k+3] = v.w;
    }
    float wih  = Wih[lane];
    float bsum = bih[lane] + bhh[lane];

    float h[16];
#pragma unroll
    for (int k = 0; k < 16; ++k) h[k] = 0.0f;
    float c = 0.0f;

    for (int s = 0; s < TT; ++s) {
        int t = dir ? (TT - 1 - s) : s;
        float xt = xrow[t];
        float g0 = fmaf(wih, xt, bsum), g1 = 0.0f;
#pragma unroll
        for (int k = 0; k < 8; ++k) {
            g0 = fmaf(whh[2*k],   h[2*k],   g0);
            g1 = fmaf(whh[2*k+1], h[2*k+1], g1);
        }
        float hj = cellstep_(g0 + g1, lane, c, h);
        if (lane < 16) hout[(size_t)t * strideT + lane] = __float2half(hj);
    }
#pragma unroll
    for (int k = 0; k < 16; ++k) hfin[k] = h[k];
}

// ---------- layer 1 (input dim 32 = [h0f, h0b]), one direction ----------
__device__ void lstm1_(const __half* __restrict__ inF, const __half* __restrict__ inB,
                       size_t strideT,
                       const float* __restrict__ Wih, const float* __restrict__ Whh,
                       const float* __restrict__ bih, const float* __restrict__ bhh,
                       int dir, int lane, float hfin[16]) {
    float wih[32];
#pragma unroll
    for (int k = 0; k < 8; ++k) {
        float4 v = ((const float4*)(Wih + lane * 32))[k];
        wih[4*k] = v.x; wih[4*k+1] = v.y; wih[4*k+2] = v.z; wih[4*k+3] = v.w;
    }
    float whh[16];
#pragma unroll
    for (int k = 0; k < 4; ++k) {
        float4 v = ((const float4*)(Whh + lane * 16))[k];
        whh[4*k] = v.x; whh[4*k+1] = v.y; whh[4*k+2] = v.z; whh[4*k+3] = v.w;
    }
    float bsum = bih[lane] + bhh[lane];

    float h[16];
#pragma unroll
    for (int k = 0; k < 16; ++k) h[k] = 0.0f;
    float c = 0.0f;

    for (int s = 0; s < TT; ++s) {
        int t = dir ? (TT - 1 - s) : s;
        float xf[16], xb[16];
        load16h_(inF + (size_t)t * strideT, xf);
        load16h_(inB + (size_t)t * strideT, xb);

        float g0 = bsum, g1 = 0.0f, g2 = 0.0f, g3 = 0.0f;
#pragma unroll
        for (int k = 0; k < 4; ++k) {
            g0 = fmaf(wih[4*k],   xf[4*k],   g0);
            g1 = fmaf(wih[4*k+1], xf[4*k+1], g1);
            g2 = fmaf(wih[4*k+2], xf[4*k+2], g2);
            g3 = fmaf(wih[4*k+3], xf[4*k+3], g3);
        }
#pragma unroll
        for (int k = 0; k < 4; ++k) {
            g0 = fmaf(wih[16+4*k],   xb[4*k],   g0);
            g1 = fmaf(wih[16+4*k+1], xb[4*k+1], g1);
            g2 = fmaf(wih[16+4*k+2], xb[4*k+2], g2);
            g3 = fmaf(wih[16+4*k+3], xb[4*k+3], g3);
        }
#pragma unroll
        for (int k = 0; k < 4; ++k) {
            g0 = fmaf(whh[4*k],   h[4*k],   g0);
            g1 = fmaf(whh[4*k+1], h[4*k+1], g1);
            g2 = fmaf(whh[4*k+2], h[4*k+2], g2);
            g3 = fmaf(whh[4*k+3], h[4*k+3], g3);
        }
        (void)cellstep_((g0 + g1) + (g2 + g3), lane, c, h);
    }
#pragma unroll
    for (int k = 0; k < 16; ++k) hfin[k] = h[k];
}

// ---------- parameters ----------
struct Params {
    const float *x;
    const float *Wih0f, *Whh0f, *bih0f, *bhh0f;
    const float *Wih0b, *Whh0b, *bih0b, *bhh0b;
    const float *Wih1f, *Whh1f, *bih1f, *bhh1f;
    const float *Wih1b, *Whh1b, *bih1b, *bhh1b;
    const float *W1, *b1, *W2, *b2;
    float* out;
    __half* wsF;   // [T][B][H] fp16
    __half* wsB;   // [T][B][H] fp16
};

__global__ __launch_bounds__(256) void lstm_bidir_kernel(Params p) {
    int lane = threadIdx.x & 63;
    int w    = threadIdx.x >> 6;
    int b    = blockIdx.x * 4 + w;

    const float* xrow = p.x + (size_t)b * TT;
    size_t strideT = (size_t)BB * HH;
    __half* wsF = p.wsF + (size_t)b * HH;
    __half* wsB = p.wsB + (size_t)b * HH;

    float htmp[16];
    lstm0_(xrow, p.Wih0f, p.Whh0f, p.bih0f, p.bhh0f, 0, wsF, strideT, lane, htmp);
    lstm0_(xrow, p.Wih0b, p.Whh0b, p.bih0b, p.bhh0b, 1, wsB, strideT, lane, htmp);

    float hTf[16], hTb[16];
    lstm1_(wsF, wsB, strideT, p.Wih1f, p.Whh1f, p.bih1f, p.bhh1f, 0, lane, hTf);
    lstm1_(wsF, wsB, strideT, p.Wih1b, p.Whh1b, p.bih1b, p.bhh1b, 1, lane, hTb);

    // head: feat = [hTb, hTf]; z=elu(feat); z=elu(z@W1.T+b1); z=elu(z@W2.T+b2)
    float z1 = 0.0f;
    if (lane < 25) {
        float acc = p.b1[lane];
        const float* w1 = p.W1 + lane * 32;
#pragma unroll
        for (int k = 0; k < 16; ++k) acc = fmaf(w1[k],      elu_(hTb[k]), acc);
#pragma unroll
        for (int k = 0; k < 16; ++k) acc = fmaf(w1[16 + k], elu_(hTf[k]), acc);
        z1 = elu_(acc);
    }
    float z1v[25];
#pragma unroll
    for (int k = 0; k < 25; ++k) z1v[k] = bcast_(z1, k);

    if (lane < 20) {
        float acc = p.b2[lane];
        const float* w2 = p.W2 + lane * 25;
#pragma unroll
        for (int k = 0; k < 25; ++k) acc = fmaf(w2[k], z1v[k], acc);
        p.out[(size_t)b * 20 + lane] = elu_(acc);
    }
}

extern "C" void kernel_launch(void* const* d_in, const int* in_sizes, int n_in,
                              void* d_out, int out_size, void* d_ws, size_t ws_size,
                              hipStream_t stream) {
    Params p;
    p.x     = (const float*)d_in[0];
    p.Wih0f = (const float*)d_in[1];  p.Whh0f = (const float*)d_in[2];
    p.bih0f = (const float*)d_in[3];  p.bhh0f = (const float*)d_in[4];
    p.Wih0b = (const float*)d_in[5];  p.Whh0b = (const float*)d_in[6];
    p.bih0b = (const float*)d_in[7];  p.bhh0b = (const float*)d_in[8];
    p.Wih1f = (const float*)d_in[9];  p.Whh1f = (const float*)d_in[10];
    p.bih1f = (const float*)d_in[11]; p.bhh1f = (const float*)d_in[12];
    p.Wih1b = (const float*)d_in[13]; p.Whh1b = (const float*)d_in[14];
    p.bih1b = (const float*)d_in[15]; p.bhh1b = (const float*)d_in[16];
    p.W1 = (const float*)d_in[17]; p.b1 = (const float*)d_in[18];
    p.W2 = (const float*)d_in[19]; p.b2 = (const float*)d_in[20];
    p.out = (float*)d_out;
    // workspace: 2 buffers of [T][B][H] fp16 = 2*512*4096*16*2 = 128 MiB
    p.wsF = (__half*)d_ws;
    p.wsB = (__half*)d_ws + (size_t)TT * BB * HH;

    dim3 grid(BB / 4);   // 4 waves (batch elements) per 256-thread block
    dim3 block(256);
    hipLaunchKernelGGL(lstm_bidir_kernel, grid, block, 0, stream, p);
}

// Round 2
// 573.064 us; speedup vs baseline: 2.4385x; 2.4385x over previous
//
#include <hip/hip_runtime.h>
#include <hip/hip_fp16.h>
#include <stdint.h>

#define TT 512
#define BB 4096
#define NTILE 256   // BB/16 batch tiles

typedef _Float16 half8_t __attribute__((ext_vector_type(8)));
typedef float f32x4 __attribute__((ext_vector_type(4)));

union FragU { uint4 u4; half8_t h8; unsigned int u[4]; };
union H2U { unsigned int u; _Float16 h[2]; };

__device__ __forceinline__ float rcp_(float x){ return __builtin_amdgcn_rcpf(x); }
__device__ __forceinline__ float exp2_(float x){ return __builtin_amdgcn_exp2f(x); }
// sigmoid(x) = 1/(1+2^(-x*log2e))
__device__ __forceinline__ float sig_(float x){ return rcp_(1.0f + exp2_(x * -1.44269504f)); }
// tanh(x) = 2*sigmoid(2x)-1
__device__ __forceinline__ float tanhf_(float x){ return fmaf(2.0f, rcp_(1.0f + exp2_(x * -2.88539008f)), -1.0f); }
__device__ __forceinline__ float elu_(float x){ return x > 0.0f ? x : (exp2_(x * 1.44269504f) - 1.0f); }
__device__ __forceinline__ int mini_(int a, int b){ return a < b ? a : b; }

__device__ __forceinline__ f32x4 MFMA(half8_t a, half8_t b, f32x4 c) {
    return __builtin_amdgcn_mfma_f32_16x16x32_f16(a, b, c, 0, 0, 0);
}

// Load 8 consecutive f32 -> half8 (A-fragment slice). A layout for
// mfma_f32_16x16x32_f16: row = lane&15, k = 8*(lane>>4) + e.
__device__ __forceinline__ half8_t packA8(const float* s) {
    f32x4 a = *(const f32x4*)s; f32x4 b = *(const f32x4*)(s + 4);
    half8_t h;
    h[0]=(_Float16)a[0]; h[1]=(_Float16)a[1]; h[2]=(_Float16)a[2]; h[3]=(_Float16)a[3];
    h[4]=(_Float16)b[0]; h[5]=(_Float16)b[1]; h[6]=(_Float16)b[2]; h[7]=(_Float16)b[3];
    return h;
}

// Per-lane recurrent state: lane (q = lane>>4, b = lane&15) owns hidden units
// j = 4q+r (r=0..3) of batch column b: cell c, h (f32), and h packed as
// fp16 hi + fp16 residual lo (hi/lo feed the K=32 [h_hi;h_lo] B-fragment).
struct State {
    float c0, c1, c2, c3;
    float h0, h1, h2, h3;
    unsigned int hh01, hh23, hl01, hl23;
};

// gi/gf/gg/go = C-fragments of M-tiles 0..3: reg r of lane (q,b) is gate
// (16m + 4q + r) for batch b -> exactly (i,f,g,o) of hidden j=4q+r. Lane-local.
__device__ __forceinline__ void cell_update(State& st, f32x4 gi, f32x4 gf, f32x4 gg, f32x4 go) {
    {   float i=sig_(gi[0]), f=sig_(gf[0]), g=tanhf_(gg[0]), o=sig_(go[0]);
        st.c0 = fmaf(f, st.c0, i*g); st.h0 = o * tanhf_(st.c0); }
    {   float i=sig_(gi[1]), f=sig_(gf[1]), g=tanhf_(gg[1]), o=sig_(go[1]);
        st.c1 = fmaf(f, st.c1, i*g); st.h1 = o * tanhf_(st.c1); }
    {   float i=sig_(gi[2]), f=sig_(gf[2]), g=tanhf_(gg[2]), o=sig_(go[2]);
        st.c2 = fmaf(f, st.c2, i*g); st.h2 = o * tanhf_(st.c2); }
    {   float i=sig_(gi[3]), f=sig_(gf[3]), g=tanhf_(gg[3]), o=sig_(go[3]);
        st.c3 = fmaf(f, st.c3, i*g); st.h3 = o * tanhf_(st.c3); }
    // pack hi (RNE) + residual lo
    H2U a; a.h[0]=(_Float16)st.h0; a.h[1]=(_Float16)st.h1; st.hh01 = a.u;
    H2U b; b.h[0]=(_Float16)st.h2; b.h[1]=(_Float16)st.h3; st.hh23 = b.u;
    float r0 = st.h0 - (float)a.h[0], r1 = st.h1 - (float)a.h[1];
    float r2 = st.h2 - (float)b.h[0], r3 = st.h3 - (float)b.h[1];
    H2U c; c.h[0]=(_Float16)r0; c.h[1]=(_Float16)r1; st.hl01 = c.u;
    H2U d; d.h[0]=(_Float16)r2; d.h[1]=(_Float16)r3; st.hl23 = d.u;
}

// Build next-step B-fragment [h_hi(k=0..15); h_lo(k=16..31)].
// Target lane (q,b), halves e=0..7 <-> k=8q+e: pulls j=8q'..8q'+7 (q'=q&1 side)
// from source lanes srcA=(q&1)*32+b (j base) and srcB=srcA+16 (j base+4);
// hi for q<2, lo for q>=2.
__device__ __forceinline__ uint4 build_frag(const State& st, int srcA, int srcB, bool lo) {
    unsigned int a0 = (unsigned int)__shfl((int)st.hh01, srcA);
    unsigned int a1 = (unsigned int)__shfl((int)st.hh23, srcA);
    unsigned int a2 = (unsigned int)__shfl((int)st.hh01, srcB);
    unsigned int a3 = (unsigned int)__shfl((int)st.hh23, srcB);
    unsigned int l0 = (unsigned int)__shfl((int)st.hl01, srcA);
    unsigned int l1 = (unsigned int)__shfl((int)st.hl23, srcA);
    unsigned int l2 = (unsigned int)__shfl((int)st.hl01, srcB);
    unsigned int l3 = (unsigned int)__shfl((int)st.hl23, srcB);
    uint4 r;
    r.x = lo ? l0 : a0; r.y = lo ? l1 : a1;
    r.z = lo ? l2 : a2; r.w = lo ? l3 : a3;
    return r;
}

// ---------------- phase A: layer 0 (input dim 1), both directions ----------------
struct PA {
    const float *x;
    const float *WihF, *WhhF, *bihF, *bhhF;
    const float *WihB, *WhhB, *bihB, *bhhB;
    uint4* ws;   // [t][tile][64] fragments: slot q*16+b holds k=8q+e of col b
};

__global__ __launch_bounds__(64) void phaseA_k(PA p) {
    const int lane = threadIdx.x;
    const int q = lane >> 4, b = lane & 15;
    const int tile = blockIdx.x >> 1, dir = blockIdx.x & 1;
    const float* Wih = dir ? p.WihB : p.WihF;
    const float* Whh = dir ? p.WhhB : p.WhhF;
    const float* bih = dir ? p.bihB : p.bihF;
    const float* bhh = dir ? p.bhhB : p.bhhF;

    half8_t whhF[4]; f32x4 biasF[4]; f32x4 wihA[4];
#pragma unroll
    for (int m = 0; m < 4; ++m) {
        // A = [Whh | Whh] (K=32): k<16 -> Whh[:,k], k>=16 -> Whh[:,k-16]
        whhF[m] = packA8(Whh + (16*m + b)*16 + 8*(q & 1));
        f32x4 bi = *(const f32x4*)(bih + 16*m + 4*q);
        f32x4 bh = *(const f32x4*)(bhh + 16*m + 4*q);
        biasF[m] = bi + bh;
        wihA[m] = *(const f32x4*)(Wih + 16*m + 4*q);   // Wih0 is [64x1]
    }

    State st; st.c0=st.c1=st.c2=st.c3=0.f; st.h0=st.h1=st.h2=st.h3=0.f;
    st.hh01=st.hh23=st.hl01=st.hl23=0u;
    const int srcA = (q & 1)*32 + b, srcB = srcA + 16;
    const bool lo = q >= 2;

    const float* xrow = p.x + (size_t)(tile*16 + b) * TT;
    uint4* wsp = p.ws + (size_t)tile*64 + (size_t)(dir*2 + q)*16 + b;

    uint4 frag; frag.x = frag.y = frag.z = frag.w = 0u;

    float xb[4];
#pragma unroll
    for (int u = 0; u < 4; ++u) xb[u] = xrow[dir ? (TT-1-u) : u];

    for (int g = 0; g < TT/4; ++g) {
        const int s0 = g*4;
        float nb[4];
#pragma unroll
        for (int u = 0; u < 4; ++u) {
            int sp = mini_(s0 + 4 + u, TT-1);
            nb[u] = xrow[dir ? (TT-1-sp) : sp];
        }
#pragma unroll
        for (int u = 0; u < 4; ++u) {
            const int s = s0 + u;
            const int t = dir ? (TT-1-s) : s;
            FragU hf; hf.u4 = frag;
            f32x4 a0 = MFMA(whhF[0], hf.h8, biasF[0]);
            f32x4 a1 = MFMA(whhF[1], hf.h8, biasF[1]);
            f32x4 a2 = MFMA(whhF[2], hf.h8, biasF[2]);
            f32x4 a3 = MFMA(whhF[3], hf.h8, biasF[3]);
            const float xv = xb[u];
            a0 += wihA[0] * xv; a1 += wihA[1] * xv;
            a2 += wihA[2] * xv; a3 += wihA[3] * xv;
            cell_update(st, a0, a1, a2, a3);
            frag = build_frag(st, srcA, srcB, lo);
            if (q < 2) wsp[(size_t)t * (NTILE*64)] = frag;  // hi halves = h0[t] fp16
        }
#pragma unroll
        for (int u = 0; u < 4; ++u) xb[u] = nb[u];
    }
}

// ---------------- phase B: layer 1 (input dim 32 from ws), both directions ----------------
struct PB {
    const float *WihF, *WhhF, *bihF, *bhhF;
    const float *WihB, *WhhB, *bihB, *bhhB;
    const uint4* ws;
    float* hT;   // [dir][tile][b][16] f32
};

__global__ __launch_bounds__(64) void phaseB_k(PB p) {
    const int lane = threadIdx.x;
    const int q = lane >> 4, b = lane & 15;
    const int tile = blockIdx.x >> 1, dir = blockIdx.x & 1;
    const float* Wih = dir ? p.WihB : p.WihF;
    const float* Whh = dir ? p.WhhB : p.WhhF;
    const float* bih = dir ? p.bihB : p.bihF;
    const float* bhh = dir ? p.bhhB : p.bhhF;

    half8_t wihF[4], whhF[4]; f32x4 biasF[4];
#pragma unroll
    for (int m = 0; m < 4; ++m) {
        wihF[m] = packA8(Wih + (16*m + b)*32 + 8*q);          // K=32 = [h0f;h0b]
        whhF[m] = packA8(Whh + (16*m + b)*16 + 8*(q & 1));    // [Whh | Whh]
        f32x4 bi = *(const f32x4*)(bih + 16*m + 4*q);
        f32x4 bh = *(const f32x4*)(bhh + 16*m + 4*q);
        biasF[m] = bi + bh;
    }

    State st; st.c0=st.c1=st.c2=st.c3=0.f; st.h0=st.h1=st.h2=st.h3=0.f;
    st.hh01=st.hh23=st.hl01=st.hl23=0u;
    const int srcA = (q & 1)*32 + b, srcB = srcA + 16;
    const bool lo = q >= 2;

    const uint4* wsp = p.ws + (size_t)tile*64 + lane;
    uint4 frag; frag.x = frag.y = frag.z = frag.w = 0u;

    uint4 xb[4];
#pragma unroll
    for (int u = 0; u < 4; ++u) {
        int t = dir ? (TT-1-u) : u;
        xb[u] = wsp[(size_t)t * (NTILE*64)];
    }

    for (int g = 0; g < TT/4; ++g) {
        const int s0 = g*4;
        uint4 nb[4];
#pragma unroll
        for (int u = 0; u < 4; ++u) {
            int sp = mini_(s0 + 4 + u, TT-1);
            int t = dir ? (TT-1-sp) : sp;
            nb[u] = wsp[(size_t)t * (NTILE*64)];
        }
#pragma unroll
        for (int u = 0; u < 4; ++u) {
            FragU xf; xf.u4 = xb[u];
            FragU hf; hf.u4 = frag;
            f32x4 a0 = MFMA(wihF[0], xf.h8, biasF[0]);
            f32x4 a1 = MFMA(wihF[1], xf.h8, biasF[1]);
            f32x4 a2 = MFMA(wihF[2], xf.h8, biasF[2]);
            f32x4 a3 = MFMA(wihF[3], xf.h8, biasF[3]);
            a0 = MFMA(whhF[0], hf.h8, a0);
            a1 = MFMA(whhF[1], hf.h8, a1);
            a2 = MFMA(whhF[2], hf.h8, a2);
            a3 = MFMA(whhF[3], hf.h8, a3);
            cell_update(st, a0, a1, a2, a3);
            frag = build_frag(st, srcA, srcB, lo);
        }
#pragma unroll
        for (int u = 0; u < 4; ++u) xb[u] = nb[u];
    }

    float* hp = p.hT + ((size_t)(dir*NTILE + tile)*16 + b)*16 + 4*q;
    f32x4 hv; hv[0]=st.h0; hv[1]=st.h1; hv[2]=st.h2; hv[3]=st.h3;
    *(f32x4*)hp = hv;
}

// ---------------- phase C: MLP head ----------------
struct PC {
    const float* hT;
    const float *W1, *b1, *W2, *b2;
    float* out;
};

__global__ __launch_bounds__(64) void head_k(PC p) {
    const int B = blockIdx.x * 64 + threadIdx.x;
    const int tile = B >> 4, b = B & 15;
    const float* hf = p.hT + ((size_t)tile*16 + b)*16;
    const float* hb = p.hT + ((size_t)(NTILE + tile)*16 + b)*16;

    float z0[32];
#pragma unroll
    for (int k = 0; k < 16; ++k) z0[k] = elu_(hb[k]);       // feat = [hT_b, hT_f]
#pragma unroll
    for (int k = 0; k < 16; ++k) z0[16+k] = elu_(hf[k]);

    float z1[25];
#pragma unroll
    for (int o = 0; o < 25; ++o) {
        float a = p.b1[o];
#pragma unroll
        for (int k = 0; k < 32; ++k) a = fmaf(p.W1[o*32 + k], z0[k], a);
        z1[o] = elu_(a);
    }
#pragma unroll
    for (int o = 0; o < 20; ++o) {
        float a = p.b2[o];
#pragma unroll
        for (int k = 0; k < 25; ++k) a = fmaf(p.W2[o*25 + k], z1[k], a);
        p.out[(size_t)B*20 + o] = elu_(a);
    }
}

extern "C" void kernel_launch(void* const* d_in, const int* in_sizes, int n_in,
                              void* d_out, int out_size, void* d_ws, size_t ws_size,
                              hipStream_t stream) {
    (void)in_sizes; (void)n_in; (void)out_size;

    const size_t frag_bytes = (size_t)TT * NTILE * 64 * sizeof(uint4);     // 128 MiB
    const size_t hT_bytes   = (size_t)2 * NTILE * 16 * 16 * sizeof(float); // 512 KiB
    size_t hT_off = (ws_size >= frag_bytes + hT_bytes) ? frag_bytes
                                                       : (ws_size - hT_bytes);
    uint4* ws = (uint4*)d_ws;
    float* hT = (float*)((char*)d_ws + hT_off);

    PA pa;
    pa.x = (const float*)d_in[0];
    pa.WihF = (const float*)d_in[1];  pa.WhhF = (const float*)d_in[2];
    pa.bihF = (const float*)d_in[3];  pa.bhhF = (const float*)d_in[4];
    pa.WihB = (const float*)d_in[5];  pa.WhhB = (const float*)d_in[6];
    pa.bihB = (const float*)d_in[7];  pa.bhhB = (const float*)d_in[8];
    pa.ws = ws;
    hipLaunchKernelGGL(phaseA_k, dim3(NTILE*2), dim3(64), 0, stream, pa);

    PB pb;
    pb.WihF = (const float*)d_in[9];   pb.WhhF = (const float*)d_in[10];
    pb.bihF = (const float*)d_in[11];  pb.bhhF = (const float*)d_in[12];
    pb.WihB = (const float*)d_in[13];  pb.WhhB = (const float*)d_in[14];
    pb.bihB = (const float*)d_in[15];  pb.bhhB = (const float*)d_in[16];
    pb.ws = ws; pb.hT = hT;
    hipLaunchKernelGGL(phaseB_k, dim3(NTILE*2), dim3(64), 0, stream, pb);

    PC pc;
    pc.hT = hT;
    pc.W1 = (const float*)d_in[17]; pc.b1 = (const float*)d_in[18];
    pc.W2 = (const float*)d_in[19]; pc.b2 = (const float*)d_in[20];
    pc.out = (float*)d_out;
    hipLaunchKernelGGL(head_k, dim3(BB/64), dim3(64), 0, stream, pc);
}

// Round 4
// 414.288 us; speedup vs baseline: 3.3731x; 1.3832x over previous
//
#include <hip/hip_runtime.h>
#include <stdint.h>

#define TT 512
#define BB 4096
#define NTILE 256
#define LOG2E 1.4426950408889634f

typedef _Float16 half8_t __attribute__((ext_vector_type(8)));
typedef __fp16 fp16x2_t __attribute__((ext_vector_type(2)));
typedef float f32x4 __attribute__((ext_vector_type(4)));

union FragU { uint4 u4; half8_t h8; };
union PkU { fp16x2_t h2; unsigned int u; };

__device__ __forceinline__ float rcp_(float x){ return __builtin_amdgcn_rcpf(x); }
__device__ __forceinline__ float exp2_(float x){ return __builtin_amdgcn_exp2f(x); }
__device__ __forceinline__ float elu_(float x){ return x > 0.0f ? x : (exp2_(x * LOG2E) - 1.0f); }
__device__ __forceinline__ int mini_(int a, int b){ return a < b ? a : b; }
__device__ __forceinline__ float maskhi_(float x){ return __uint_as_float(__float_as_uint(x) & 0xFFFFE000u); }
__device__ __forceinline__ unsigned int pkrtz_(float a, float b){
    PkU p; p.h2 = __builtin_amdgcn_cvt_pkrtz(a, b); return p.u;
}

__device__ __forceinline__ f32x4 MFMA(half8_t a, half8_t b, f32x4 c) {
    return __builtin_amdgcn_mfma_f32_16x16x32_f16(a, b, c, 0, 0, 0);
}

__device__ __forceinline__ f32x4 ld4_(const float* p){ return *(const f32x4*)p; }

// pack 8 f32 -> 8 f16 with scale (A-fragment slice; row = lane&15, k = 8*(lane>>4)+e)
__device__ __forceinline__ half8_t packA8s(const float* s, float sc) {
    half8_t h;
#pragma unroll
    for (int k = 0; k < 8; ++k) h[k] = (_Float16)(s[k] * sc);
    return h;
}

// Gate activations. Inputs PRESCALED: i,f,o rows by log2e; g rows by 2*log2e.
// sigmoid(x) = rcp(1 + exp2(-x*log2e)); tanh(x) = 2*rcp(1+exp2(-2x*log2e)) - 1.
__device__ __forceinline__ void cell4_(f32x4 gi, f32x4 gf, f32x4 gg, f32x4 go,
                                       f32x4& c, f32x4& h) {
#pragma unroll
    for (int r = 0; r < 4; ++r) {
        float I = rcp_(1.0f + exp2_(-gi[r]));
        float F = rcp_(1.0f + exp2_(-gf[r]));
        float G = fmaf(2.0f, rcp_(1.0f + exp2_(-gg[r])), -1.0f);
        float O = rcp_(1.0f + exp2_(-go[r]));
        float cc = fmaf(F, c[r], I * G);
        c[r] = cc;
        float th = fmaf(2.0f, rcp_(1.0f + exp2_(cc * (-2.0f * LOG2E))), -1.0f);
        h[r] = O * th;
    }
}

// h -> fp16 hi (exact mantissa truncation) + fp16 residual lo
__device__ __forceinline__ void packHL_(const f32x4 h, uint2& hh, uint2& hl) {
    float m0 = maskhi_(h[0]), m1 = maskhi_(h[1]), m2 = maskhi_(h[2]), m3 = maskhi_(h[3]);
    hh.x = pkrtz_(m0, m1);          hh.y = pkrtz_(m2, m3);
    hl.x = pkrtz_(h[0]-m0, h[1]-m1); hl.y = pkrtz_(h[2]-m2, h[3]-m3);
}

// LDS h-exchange layout per wave: 16 cols x 80B (pad to 80 keeps 16-align, 2-way banks).
// Col b: bytes [0..31]=hi units 0..15, [32..63]=lo units 0..15.
// Write: lane(q,b) hh -> b*80+q*8, hl -> +32.  Read: lane(q,b) b128 at b*80+q*16
// == [hi u0-7 | hi u8-15 | lo u0-7 | lo u8-15] for q=0..3 (bit-identical to the
// HW-verified round-2 B-fragment: col=b, k=8q+e over K=32=[h_hi;h_lo]).

// ---------------- phase A: layer 0 (input dim 1), both directions ----------------
struct PA {
    const float *x;
    const float *WihF, *WhhF, *bihF, *bhhF;
    const float *WihB, *WhhB, *bihB, *bhhB;
    char* ws;   // [tile][t][1KB]: per (tile,t): [f u0-15 hi | b u0-15 hi] as halfs
};

__global__ __launch_bounds__(64) void phaseA_k(PA p) {
    __shared__ uint4 lds4[80];
    char* lds = (char*)lds4;
    const int lane = threadIdx.x;
    const int q = lane >> 4, b = lane & 15;
    const int tile = blockIdx.x >> 1, dir = blockIdx.x & 1;

    const float* Wih = dir ? p.WihB : p.WihF;
    const float* Whh = dir ? p.WhhB : p.WhhF;
    const float* bih = dir ? p.bihB : p.bihF;
    const float* bhh = dir ? p.bhhB : p.bhhF;

    const float SC0 = LOG2E, SC1 = LOG2E, SC2 = 2.0f*LOG2E, SC3 = LOG2E;

    // A = [Whh | Whh] over K=32 (hi;lo halves use same weights)
    half8_t whh0 = packA8s(Whh + (     b)*16 + 8*(q&1), SC0);
    half8_t whh1 = packA8s(Whh + (16 + b)*16 + 8*(q&1), SC1);
    half8_t whh2 = packA8s(Whh + (32 + b)*16 + 8*(q&1), SC2);
    half8_t whh3 = packA8s(Whh + (48 + b)*16 + 8*(q&1), SC3);

    f32x4 bias0 = (ld4_(bih +      4*q) + ld4_(bhh +      4*q)) * SC0;
    f32x4 bias1 = (ld4_(bih + 16 + 4*q) + ld4_(bhh + 16 + 4*q)) * SC1;
    f32x4 bias2 = (ld4_(bih + 32 + 4*q) + ld4_(bhh + 32 + 4*q)) * SC2;
    f32x4 bias3 = (ld4_(bih + 48 + 4*q) + ld4_(bhh + 48 + 4*q)) * SC3;

    f32x4 wihx0 = ld4_(Wih +      4*q) * SC0;   // Wih0 is [64 x 1]
    f32x4 wihx1 = ld4_(Wih + 16 + 4*q) * SC1;
    f32x4 wihx2 = ld4_(Wih + 32 + 4*q) * SC2;
    f32x4 wihx3 = ld4_(Wih + 48 + 4*q) * SC3;

    const int wr = b*80 + q*8;
    const int rd = b*80 + q*16;
    { uint2 z; z.x = 0u; z.y = 0u;
      *(uint2*)(lds + wr) = z; *(uint2*)(lds + wr + 32) = z; }
    __builtin_amdgcn_wave_barrier();

    f32x4 c = {0.f,0.f,0.f,0.f}, h = {0.f,0.f,0.f,0.f};

    const char* xbase = (const char*)p.x + (size_t)tile*16*TT*4;  // uniform
    const int   xoff  = b*TT*4;                                   // invariant voffset
    char*       wsbase = p.ws + (size_t)tile*TT*1024;             // uniform
    const int   woff  = b*64 + dir*32 + q*8;

    auto xld = [&](int u)->float {
        int s = mini_(u, TT-1);
        int t = dir ? (TT-1-s) : s;
        return *(const float*)(xbase + (size_t)t*4 + xoff);
    };

    auto step = [&](float xv, int t) {
        FragU hf; hf.u4 = *(const uint4*)(lds + rd);
        f32x4 a0 = bias0 + wihx0 * xv;
        f32x4 a1 = bias1 + wihx1 * xv;
        f32x4 a2 = bias2 + wihx2 * xv;
        f32x4 a3 = bias3 + wihx3 * xv;
        a0 = MFMA(whh0, hf.h8, a0);
        a1 = MFMA(whh1, hf.h8, a1);
        a2 = MFMA(whh2, hf.h8, a2);
        a3 = MFMA(whh3, hf.h8, a3);
        cell4_(a0, a1, a2, a3, c, h);
        uint2 hh, hl; packHL_(h, hh, hl);
        *(uint2*)(lds + wr) = hh;
        *(uint2*)(lds + wr + 32) = hl;
        *(uint2*)(wsbase + (size_t)t*1024 + woff) = hh;
        __builtin_amdgcn_wave_barrier();
    };

    float xv0 = xld(0), xv1 = xld(1), xv2 = xld(2), xv3 = xld(3);
    for (int s = 0; s < TT; s += 4) {
        const int t0 = dir ? (TT-1-s) : s;
        const int d  = dir ? -1 : 1;
        step(xv0, t0      ); xv0 = xld(s+4);
        step(xv1, t0 + d  ); xv1 = xld(s+5);
        step(xv2, t0 + 2*d); xv2 = xld(s+6);
        step(xv3, t0 + 3*d); xv3 = xld(s+7);
    }
}

// ---------------- phase B: layer 1 (input dim 32 from ws), both directions ----------------
struct PB {
    const float *WihF, *WhhF, *bihF, *bhhF;
    const float *WihB, *WhhB, *bihB, *bhhB;
    const char* ws;
    float* hT;   // [dir][tile][b][16] f32
};

__global__ __launch_bounds__(64) void phaseB_k(PB p) {
    __shared__ uint4 lds4[80];
    char* lds = (char*)lds4;
    const int lane = threadIdx.x;
    const int q = lane >> 4, b = lane & 15;
    const int tile = blockIdx.x >> 1, dir = blockIdx.x & 1;

    const float* Wih = dir ? p.WihB : p.WihF;
    const float* Whh = dir ? p.WhhB : p.WhhF;
    const float* bih = dir ? p.bihB : p.bihF;
    const float* bhh = dir ? p.bhhB : p.bhhF;

    const float SC0 = LOG2E, SC1 = LOG2E, SC2 = 2.0f*LOG2E, SC3 = LOG2E;

    half8_t wih0 = packA8s(Wih + (     b)*32 + 8*q, SC0);  // K=32 = [h0f;h0b]
    half8_t wih1 = packA8s(Wih + (16 + b)*32 + 8*q, SC1);
    half8_t wih2 = packA8s(Wih + (32 + b)*32 + 8*q, SC2);
    half8_t wih3 = packA8s(Wih + (48 + b)*32 + 8*q, SC3);

    half8_t whh0 = packA8s(Whh + (     b)*16 + 8*(q&1), SC0);
    half8_t whh1 = packA8s(Whh + (16 + b)*16 + 8*(q&1), SC1);
    half8_t whh2 = packA8s(Whh + (32 + b)*16 + 8*(q&1), SC2);
    half8_t whh3 = packA8s(Whh + (48 + b)*16 + 8*(q&1), SC3);

    f32x4 bias0 = (ld4_(bih +      4*q) + ld4_(bhh +      4*q)) * SC0;
    f32x4 bias1 = (ld4_(bih + 16 + 4*q) + ld4_(bhh + 16 + 4*q)) * SC1;
    f32x4 bias2 = (ld4_(bih + 32 + 4*q) + ld4_(bhh + 32 + 4*q)) * SC2;
    f32x4 bias3 = (ld4_(bih + 48 + 4*q) + ld4_(bhh + 48 + 4*q)) * SC3;

    const int wr = b*80 + q*8;
    const int rd = b*80 + q*16;
    { uint2 z; z.x = 0u; z.y = 0u;
      *(uint2*)(lds + wr) = z; *(uint2*)(lds + wr + 32) = z; }
    __builtin_amdgcn_wave_barrier();

    f32x4 c = {0.f,0.f,0.f,0.f}, h = {0.f,0.f,0.f,0.f};

    const char* wsbase = p.ws + (size_t)tile*TT*1024;  // uniform
    const int   xoff   = b*64 + q*16;                  // invariant voffset

    auto xld = [&](int u)->uint4 {
        int s = mini_(u, TT-1);
        int t = dir ? (TT-1-s) : s;
        return *(const uint4*)(wsbase + (size_t)t*1024 + xoff);
    };

    auto step = [&](uint4 xin) {
        FragU xf; xf.u4 = xin;
        FragU hf; hf.u4 = *(const uint4*)(lds + rd);
        f32x4 a0 = MFMA(wih0, xf.h8, bias0);
        f32x4 a1 = MFMA(wih1, xf.h8, bias1);
        f32x4 a2 = MFMA(wih2, xf.h8, bias2);
        f32x4 a3 = MFMA(wih3, xf.h8, bias3);
        a0 = MFMA(whh0, hf.h8, a0);
        a1 = MFMA(whh1, hf.h8, a1);
        a2 = MFMA(whh2, hf.h8, a2);
        a3 = MFMA(whh3, hf.h8, a3);
        cell4_(a0, a1, a2, a3, c, h);
        uint2 hh, hl; packHL_(h, hh, hl);
        *(uint2*)(lds + wr) = hh;
        *(uint2*)(lds + wr + 32) = hl;
        __builtin_amdgcn_wave_barrier();
    };

    uint4 xb0 = xld(0), xb1 = xld(1), xb2 = xld(2), xb3 = xld(3);
    for (int s = 0; s < TT; s += 4) {
        step(xb0); xb0 = xld(s+4);
        step(xb1); xb1 = xld(s+5);
        step(xb2); xb2 = xld(s+6);
        step(xb3); xb3 = xld(s+7);
    }

    float* hp = p.hT + ((size_t)(dir*NTILE + tile)*16 + b)*16 + 4*q;
    *(f32x4*)hp = h;
}

// ---------------- phase C: MLP head ----------------
struct PC {
    const float* hT;
    const float *W1, *b1, *W2, *b2;
    float* out;
};

__global__ __launch_bounds__(64) void head_k(PC p) {
    const int B = blockIdx.x * 64 + threadIdx.x;
    const int tile = B >> 4, b = B & 15;
    const float* hf = p.hT + ((size_t)tile*16 + b)*16;
    const float* hb = p.hT + ((size_t)(NTILE + tile)*16 + b)*16;

    float z0[32];
#pragma unroll
    for (int k = 0; k < 16; ++k) z0[k] = elu_(hb[k]);       // feat = [hT_b, hT_f]
#pragma unroll
    for (int k = 0; k < 16; ++k) z0[16+k] = elu_(hf[k]);

    float z1[25];
#pragma unroll
    for (int o = 0; o < 25; ++o) {
        float a = p.b1[o];
#pragma unroll
        for (int k = 0; k < 32; ++k) a = fmaf(p.W1[o*32 + k], z0[k], a);
        z1[o] = elu_(a);
    }
#pragma unroll
    for (int o = 0; o < 20; ++o) {
        float a = p.b2[o];
#pragma unroll
        for (int k = 0; k < 25; ++k) a = fmaf(p.W2[o*25 + k], z1[k], a);
        p.out[(size_t)B*20 + o] = elu_(a);
    }
}

extern "C" void kernel_launch(void* const* d_in, const int* in_sizes, int n_in,
                              void* d_out, int out_size, void* d_ws, size_t ws_size,
                              hipStream_t stream) {
    (void)in_sizes; (void)n_in; (void)out_size;

    const size_t frag_bytes = (size_t)NTILE * TT * 1024;                   // 128 MiB
    const size_t hT_bytes   = (size_t)2 * NTILE * 16 * 16 * sizeof(float); // 512 KiB
    size_t hT_off = (ws_size >= frag_bytes + hT_bytes) ? frag_bytes
                                                       : (ws_size - hT_bytes);
    char* ws = (char*)d_ws;
    float* hT = (float*)(ws + hT_off);

    PA pa;
    pa.x = (const float*)d_in[0];
    pa.WihF = (const float*)d_in[1];  pa.WhhF = (const float*)d_in[2];
    pa.bihF = (const float*)d_in[3];  pa.bhhF = (const float*)d_in[4];
    pa.WihB = (const float*)d_in[5];  pa.WhhB = (const float*)d_in[6];
    pa.bihB = (const float*)d_in[7];  pa.bhhB = (const float*)d_in[8];
    pa.ws = ws;
    hipLaunchKernelGGL(phaseA_k, dim3(NTILE*2), dim3(64), 0, stream, pa);

    PB pb;
    pb.WihF = (const float*)d_in[9];   pb.WhhF = (const float*)d_in[10];
    pb.bihF = (const float*)d_in[11];  pb.bhhF = (const float*)d_in[12];
    pb.WihB = (const float*)d_in[13];  pb.WhhB = (const float*)d_in[14];
    pb.bihB = (const float*)d_in[15];  pb.bhhB = (const float*)d_in[16];
    pb.ws = ws; pb.hT = hT;
    hipLaunchKernelGGL(phaseB_k, dim3(NTILE*2), dim3(64), 0, stream, pb);

    PC pc;
    pc.hT = hT;
    pc.W1 = (const float*)d_in[17]; pc.b1 = (const float*)d_in[18];
    pc.W2 = (const float*)d_in[19]; pc.b2 = (const float*)d_in[20];
    pc.out = (float*)d_out;
    hipLaunchKernelGGL(head_k, dim3(BB/64), dim3(64), 0, stream, pc);
}